// Round 5
// baseline (507.419 us; speedup 1.0000x reference)
//
#include <hip/hip_runtime.h>
#include <hip/hip_bf16.h>

typedef unsigned short u16;
typedef __bf16 bf16x8 __attribute__((ext_vector_type(8)));
typedef float  f32x4  __attribute__((ext_vector_type(4)));

__device__ __forceinline__ unsigned pk2(float a, float b) {
    __hip_bfloat162 h = __float22bfloat162_rn(make_float2(a, b));
    unsigned u; __builtin_memcpy(&u, &h, 4);
    return u;   // low 16 = bf16(a), high 16 = bf16(b)
}
__device__ __forceinline__ u16 f2b1(float f) { return (u16)(pk2(f, f) & 0xFFFFu); }

__device__ __forceinline__ bf16x8 pack8(const float4 a, const float4 b) {
    unsigned u0 = pk2(a.x, a.y), u1 = pk2(a.z, a.w);
    unsigned u2 = pk2(b.x, b.y), u3 = pk2(b.z, b.w);
    unsigned arr[4] = {u0, u1, u2, u3};
    bf16x8 r; __builtin_memcpy(&r, arr, 16);
    return r;
}

#define MFMA __builtin_amdgcn_mfma_f32_16x16x32_bf16

// ---------------------------------------------------------------------------
// prep: ppK[r][j] = (pos_table[r].W_pos_w[j,128:256] + W_pos_b[j]) * 2*log2(e)
//       wb1/wb2/wb3: bf16 weights repacked into per-(n,kk) contiguous 1KB
//       tiles, element (row j, col t) -> [ (j>>4)*4+(t>>5) ][ j&15 ][ t&31 ]
//       (wb1 = Wpw[:, :128], wb2 = W2, wb3 = W1 for the mean-GEMM).
//       bsum[t] = W1_b[t] + W2_b[t].
// ---------------------------------------------------------------------------
__global__ __launch_bounds__(128) void prep_kernel(
    const float* __restrict__ pos_table, const float* __restrict__ Wpw,
    const float* __restrict__ Wpb, const float* __restrict__ W2,
    const float* __restrict__ W1, const float* __restrict__ W1b,
    const float* __restrict__ W2b,
    float* __restrict__ ppK, u16* __restrict__ wb1, u16* __restrict__ wb2,
    u16* __restrict__ wb3, float* __restrict__ bsum)
{
    const int b = blockIdx.x, t = threadIdx.x;
    if (b < 65) {
        const float4* pr = (const float4*)(pos_table + b * 128);
        const float4* wr = (const float4*)(Wpw + t * 256 + 128);
        float acc = Wpb[t];
        #pragma unroll
        for (int k = 0; k < 32; ++k) {
            const float4 p = pr[k], wv = wr[k];
            acc += p.x * wv.x + p.y * wv.y + p.z * wv.z + p.w * wv.w;
        }
        ppK[b * 128 + t] = acc * 2.885390081777927f;   // pre-scaled for exp2
    } else {
        const int j = b - 65;                          // output row 0..127
        const int off = (((j >> 4) * 4 + (t >> 5)) * 16 + (j & 15)) * 32 + (t & 31);
        wb1[off] = f2b1(Wpw[j * 256 + t]);
        wb2[off] = f2b1(W2[j * 128 + t]);
        wb3[off] = f2b1(W1[j * 128 + t]);
        if (j == 0) bsum[t] = W1b[t] + W2b[t];
    }
}

// ---------------------------------------------------------------------------
// fused v5: HALF-SESSION WAVES for 2x occupancy.
// v4 (1 wave = 1 session) won 208->166us but sat at 8 waves/CU (ph LDS
// 17.4KB/wave) with all pipes <26% and ~85% per-wave stall: latency-bound
// with only 2 waves/SIMD to interleave. v5: wave owns 32 tokens (2 m-tiles);
// block = 4 waves = 2 sessions; ph slice 32x136x2 = 8.7KB/wave ->
// LDS 37376B/block -> 4 blocks/CU = 16 waves/CU (VGPR capped 128 via
// __launch_bounds__(256,4)). Two light couplings return (mean-combine and
// alpha-combine barriers) -- NOT the old per-phase lockstep. Mean partial
// sums now direct LDS stores (atomics dropped).
// ---------------------------------------------------------------------------
__global__ __launch_bounds__(256, 4) void fused_kernel(
    const float* __restrict__ hidden, const int* __restrict__ rpos,
    const float* __restrict__ qw, const float* __restrict__ qb,
    const float* __restrict__ ppK, const u16* __restrict__ wb1g,
    const u16* __restrict__ wb2g, const u16* __restrict__ wb3g,
    const float* __restrict__ bsum, float* __restrict__ out)
{
    __shared__ __align__(16) u16 phs[4 * 32 * 136];  // per-wave 32x136 ph slices
    __shared__ __align__(16) float meanv[4 * 128];   // [sess][half][128] partials
    __shared__ __align__(16) float alphas[2 * 64];   // per-session alpha strips
    // total 34816 + 2048 + 512 = 37376 B -> 4 blocks/CU

    const int tid = threadIdx.x;
    const int w = tid >> 6;                 // wave 0..3
    const int l = tid & 63;
    const int c = l & 15;                   // MFMA A-row / D-col
    const int g = l >> 4;                   // quad
    const int sl = w >> 1;                  // session within block (0,1)
    const int p  = w & 1;                   // which 32-token half
    const int s  = blockIdx.x * 2 + sl;     // global session id
    const float* hs = hidden + (size_t)s * (64 * 128);
    const float* hw = hs + p * (32 * 128);  // this wave's 32 rows
    u16* ph = phs + w * (32 * 136);

    // ---- load A-frags (own 32 rows) + per-lane column partial sums
    bf16x8 af[2][4];
    float cs[4][8];
    #pragma unroll
    for (int kk = 0; kk < 4; ++kk)
        #pragma unroll
        for (int j = 0; j < 8; ++j) cs[kk][j] = 0.f;
    #pragma unroll
    for (int m = 0; m < 2; ++m)
        #pragma unroll
        for (int kk = 0; kk < 4; ++kk) {
            const float4* ptr = (const float4*)(hw + (16 * m + c) * 128 + 32 * kk + 8 * g);
            const float4 v0 = ptr[0], v1 = ptr[1];
            cs[kk][0] += v0.x; cs[kk][1] += v0.y; cs[kk][2] += v0.z; cs[kk][3] += v0.w;
            cs[kk][4] += v1.x; cs[kk][5] += v1.y; cs[kk][6] += v1.z; cs[kk][7] += v1.w;
            af[m][kk] = pack8(v0, v1);
        }

    // ---- reduce col-sums over the 16 c-lanes (masks<16 stay in g-group)
    #pragma unroll
    for (int msk = 1; msk <= 8; msk <<= 1)
        #pragma unroll
        for (int kk = 0; kk < 4; ++kk)
            #pragma unroll
            for (int j = 0; j < 8; ++j)
                cs[kk][j] += __shfl_xor(cs[kk][j], msk, 64);
    // write this half's partial sums (direct stores, disjoint slots)
    if (c < 8) {
        const int kk = c >> 1, j0 = (c & 1) * 4;
        float4 v;
        v.x = cs[kk][j0];     v.y = cs[kk][j0 + 1];
        v.z = cs[kk][j0 + 2]; v.w = cs[kk][j0 + 3];
        *(float4*)&meanv[(sl * 2 + p) * 128 + 32 * kk + 8 * g + j0] = v;
    }

    // ---- ppK row offsets for this lane's 8 output rows (int4 loads)
    int pko[2][4];
    {
        const int* rp = rpos + s * 64 + p * 32;
        #pragma unroll
        for (int m = 0; m < 2; ++m) {
            const int4 rv = *(const int4*)(rp + 16 * m + 4 * g);
            pko[m][0] = rv.x * 128 + c; pko[m][1] = rv.y * 128 + c;
            pko[m][2] = rv.z * 128 + c; pko[m][3] = rv.w * 128 + c;
        }
    }

    __syncthreads();    // B1: both halves' mean partials visible

    // ---- afm = row-uniform mean A-frag (combine halves, /64)
    bf16x8 afm[4];
    {
        const float* mv0 = meanv + (sl * 2 + 0) * 128;
        const float* mv1 = meanv + (sl * 2 + 1) * 128;
        #pragma unroll
        for (int kk = 0; kk < 4; ++kk) {
            const float4 a0 = *(const float4*)&mv0[32 * kk + 8 * g];
            const float4 a1 = *(const float4*)&mv1[32 * kk + 8 * g];
            const float4 b0 = *(const float4*)&mv0[32 * kk + 8 * g + 4];
            const float4 b1 = *(const float4*)&mv1[32 * kk + 8 * g + 4];
            float4 a, b;
            a.x = (a0.x + a1.x) * (1.f / 64.f); a.y = (a0.y + a1.y) * (1.f / 64.f);
            a.z = (a0.z + a1.z) * (1.f / 64.f); a.w = (a0.w + a1.w) * (1.f / 64.f);
            b.x = (b0.x + b1.x) * (1.f / 64.f); b.y = (b0.y + b1.y) * (1.f / 64.f);
            b.z = (b0.z + b1.z) * (1.f / 64.f); b.w = (b0.w + b1.w) * (1.f / 64.f);
            afm[kk] = pack8(a, b);
        }
    }

    // ---- GEMM1: ph = tanh(hidden @ Wpa^T + pp); D -> wave-private LDS
    {
        const u16* wb1p = wb1g + c * 32 + g * 8;
        const float K2 = 2.885390081777927f;        // 2*log2(e)
        #pragma unroll
        for (int n = 0; n < 8; ++n) {
            float ppv[2][4];
            #pragma unroll
            for (int m = 0; m < 2; ++m)
                #pragma unroll
                for (int r = 0; r < 4; ++r)
                    ppv[m][r] = ppK[pko[m][r] + 16 * n];
            const bf16x8 b0 = *(const bf16x8*)(wb1p + n * 2048);
            const bf16x8 b1 = *(const bf16x8*)(wb1p + n * 2048 + 512);
            const bf16x8 b2 = *(const bf16x8*)(wb1p + n * 2048 + 1024);
            const bf16x8 b3 = *(const bf16x8*)(wb1p + n * 2048 + 1536);
            f32x4 acc[2] = {};
            #pragma unroll
            for (int m = 0; m < 2; ++m) {
                acc[m] = MFMA(af[m][0], b0, acc[m], 0, 0, 0);
                acc[m] = MFMA(af[m][1], b1, acc[m], 0, 0, 0);
                acc[m] = MFMA(af[m][2], b2, acc[m], 0, 0, 0);
                acc[m] = MFMA(af[m][3], b3, acc[m], 0, 0, 0);
            }
            #pragma unroll
            for (int m = 0; m < 2; ++m)
                #pragma unroll
                for (int r = 0; r < 4; ++r) {
                    const float arg = fmaf(acc[m][r], K2, ppv[m][r]);
                    const float e2 = __builtin_amdgcn_exp2f(arg);
                    const float rc = __builtin_amdgcn_rcpf(e2 + 1.f);
                    ph[(16 * m + 4 * g + r) * 136 + 16 * n + c] =
                        f2b1(fmaf(-2.f, rc, 1.f));          // tanh
                }
        }
    }

    // ---- GEMM2 A-frags from wave-private ph (same-wave ds order is safe)
    bf16x8 af2[2][4];
    #pragma unroll
    for (int m = 0; m < 2; ++m)
        #pragma unroll
        for (int kk = 0; kk < 4; ++kk)
            af2[m][kk] = *(const bf16x8*)&ph[(16 * m + c) * 136 + kk * 32 + g * 8];

    // ---- GEMM2: pre = mean@W1 (MFMA C-in) + ph@W2; sigmoid; alpha partials
    {
        const u16* wb2p = wb2g + c * 32 + g * 8;
        const u16* wb3p = wb3g + c * 32 + g * 8;
        const float K1 = 1.4426950408889634f;       // log2(e)
        float prt[2][4] = {};
        #pragma unroll
        for (int n = 0; n < 8; ++n) {
            const bf16x8 m0 = *(const bf16x8*)(wb3p + n * 2048);
            const bf16x8 m1 = *(const bf16x8*)(wb3p + n * 2048 + 512);
            const bf16x8 m2 = *(const bf16x8*)(wb3p + n * 2048 + 1024);
            const bf16x8 m3 = *(const bf16x8*)(wb3p + n * 2048 + 1536);
            f32x4 accM = {};
            accM = MFMA(afm[0], m0, accM, 0, 0, 0);
            accM = MFMA(afm[1], m1, accM, 0, 0, 0);
            accM = MFMA(afm[2], m2, accM, 0, 0, 0);
            accM = MFMA(afm[3], m3, accM, 0, 0, 0);
            const bf16x8 b0 = *(const bf16x8*)(wb2p + n * 2048);
            const bf16x8 b1 = *(const bf16x8*)(wb2p + n * 2048 + 512);
            const bf16x8 b2 = *(const bf16x8*)(wb2p + n * 2048 + 1024);
            const bf16x8 b3 = *(const bf16x8*)(wb2p + n * 2048 + 1536);
            const float gvn = -K1 * bsum[16 * n + c];
            const float qv  = qw[16 * n + c];
            #pragma unroll
            for (int m = 0; m < 2; ++m) {
                f32x4 a = accM;                      // mean@W1 as C-input
                a = MFMA(af2[m][0], b0, a, 0, 0, 0);
                a = MFMA(af2[m][1], b1, a, 0, 0, 0);
                a = MFMA(af2[m][2], b2, a, 0, 0, 0);
                a = MFMA(af2[m][3], b3, a, 0, 0, 0);
                #pragma unroll
                for (int r = 0; r < 4; ++r) {
                    const float arg = fmaf(a[r], -K1, gvn);
                    const float e2 = __builtin_amdgcn_exp2f(arg);
                    const float rc = __builtin_amdgcn_rcpf(e2 + 1.f);   // sigmoid
                    prt[m][r] = fmaf(rc, qv, prt[m][r]);
                }
            }
        }
        // reduce alpha over the 16 c-lanes (cols)
        #pragma unroll
        for (int msk = 1; msk <= 8; msk <<= 1)
            #pragma unroll
            for (int m = 0; m < 2; ++m)
                #pragma unroll
                for (int r = 0; r < 4; ++r)
                    prt[m][r] += __shfl_xor(prt[m][r], msk, 64);
        if (c == 0) {
            const float qbv = qb[0];
            #pragma unroll
            for (int m = 0; m < 2; ++m)
                #pragma unroll
                for (int r = 0; r < 4; ++r)
                    alphas[sl * 64 + p * 32 + 16 * m + 4 * g + r] = prt[m][r] + qbv;
        }
    }
    __syncthreads();    // B2: both halves' alphas visible

    // ---- out[s][h] = sum_t alpha_t * hidden[t][h]; wave covers 64 h-cols
    //      (h = p*64 + l), all 64 tokens; coalesced 256B loads; 4 chains.
    {
        const int h = p * 64 + l;
        const float* alw = alphas + sl * 64;
        float a0 = 0.f, a1 = 0.f, a2 = 0.f, a3 = 0.f;
        #pragma unroll
        for (int t4 = 0; t4 < 16; ++t4) {
            const float4 av = *(const float4*)&alw[t4 * 4];
            const float* hr = hs + (t4 * 4) * 128 + h;
            a0 = fmaf(av.x, hr[0],   a0);
            a1 = fmaf(av.y, hr[128], a1);
            a2 = fmaf(av.z, hr[256], a2);
            a3 = fmaf(av.w, hr[384], a3);
        }
        out[(size_t)s * 128 + h] = (a0 + a1) + (a2 + a3);
    }
}

// ---------------------------------------------------------------------------
extern "C" void kernel_launch(void* const* d_in, const int* in_sizes, int n_in,
                              void* d_out, int out_size, void* d_ws, size_t ws_size,
                              hipStream_t stream)
{
    const float* hidden    = (const float*)d_in[0];
    const float* pos_table = (const float*)d_in[1];
    const float* Wpw       = (const float*)d_in[2];
    const float* Wpb       = (const float*)d_in[3];
    const float* W1w       = (const float*)d_in[4];
    const float* W1b       = (const float*)d_in[5];
    const float* W2w       = (const float*)d_in[6];
    const float* W2b       = (const float*)d_in[7];
    const float* qw        = (const float*)d_in[8];
    const float* qb        = (const float*)d_in[9];
    const int*   rpos      = (const int*)d_in[11];
    float* out = (float*)d_out;

    const int B = in_sizes[10];              // sessions (8192)

    // workspace layout (132096 B total)
    char* wsb = (char*)d_ws;
    float* ppK  = (float*)wsb;                           // 65*128*4 = 33280
    u16*   wb1  = (u16*)(wsb + 33280);                   // 32768
    u16*   wb2  = (u16*)(wsb + 33280 + 32768);           // 32768
    u16*   wb3  = (u16*)(wsb + 33280 + 2 * 32768);       // 32768
    float* bsum = (float*)(wsb + 33280 + 3 * 32768);     // 512

    prep_kernel<<<193, 128, 0, stream>>>(pos_table, Wpw, Wpb, W2w, W1w, W1b, W2b,
                                         ppK, wb1, wb2, wb3, bsum);
    fused_kernel<<<B / 2, 256, 0, stream>>>(hidden, rpos, qw, qb,
                                            ppK, wb1, wb2, wb3, bsum, out);
}